// Round 6
// baseline (249.827 us; speedup 1.0000x reference)
//
#include <hip/hip_runtime.h>
#include <hip/hip_bf16.h>

// CausalSelfAttention: B=4, S=2048, D=1024, H=16, Dh=64. fp32 in/out, bf16 MFMA compute.
//
// Pipeline (all on `stream`):
//   1. convert_x: x fp32 -> bf16 (8192x1024)
//   2. transpose_w: Wq|Wk|Wv -> wqkvt (3072x1024 bf16, N-major), Wo -> wot
//   3. pack_bqkv: [bq|bk|bv] -> fp32 (3072)
//   4. gemm_bt<0>: qkv = xb @ [Wq|Wk|Wv] + b -> qk bf16 (Q pre-scaled) + vt scatter.
//      R16 (re-run R17; prior submit hit an infra failure, no data): back to the
//      128^2 / BK=32 / 3-blocks-per-CU structure (cross-block overlap masks
//      barrier drains -- the 256^2 1-block/CU line plateaued at ~72us across
//      three schedules). ONE change vs the 75.7us baseline: LDS XOR-swizzle
//      sigma_r(c) = c ^ ((r>>1)&3) on the 64B rows, which R3 verified on-silicon
//      takes this geometry's read conflict to ZERO (baseline counted 6.29M
//      conflict-cycles ~= 8-way on ds_read_b128).
//   5. attn: flash attention (R11 winner, unchanged)
//   6. gemm_bt<1>: out = attn @ Wo + bo -> fp32 d_out (same swizzle fix inherited)

typedef __bf16 bf16x8 __attribute__((ext_vector_type(8)));
typedef float f32x4 __attribute__((ext_vector_type(4)));
typedef unsigned short u16;

__device__ __forceinline__ u16 f2b(float f) {
    __hip_bfloat16 h = __float2bfloat16(f);
    return __builtin_bit_cast(unsigned short, h);
}

__device__ __forceinline__ f32x4 mfma16(bf16x8 a, bf16x8 b, f32x4 c) {
    return __builtin_amdgcn_mfma_f32_16x16x32_bf16(a, b, c, 0, 0, 0);
}

typedef const __attribute__((address_space(1))) unsigned int* gas1_t;
typedef __attribute__((address_space(3))) unsigned int* las3_t;
// Async global->LDS, 16B/lane. LDS dest = wave-uniform base + lane*16 (m104/m108).
__device__ __forceinline__ void gld16(const void* g, void* l) {
    __builtin_amdgcn_global_load_lds((gas1_t)g, (las3_t)l, 16, 0, 0);
}

// ---------------------------------------------------------------- conversions
__global__ __launch_bounds__(256) void convert_x(const float* __restrict__ x,
                                                 u16* __restrict__ xb, int n4) {
    int i = blockIdx.x * 256 + threadIdx.x;
    if (i < n4) {
        float4 v = ((const float4*)x)[i];
        ushort4 u;
        u.x = f2b(v.x); u.y = f2b(v.y); u.z = f2b(v.z); u.w = f2b(v.w);
        ((ushort4*)xb)[i] = u;
    }
}

// W (K=1024 rows, N=1024 cols) fp32 -> Wt (N,K) bf16. z selects matrix.
__global__ __launch_bounds__(256) void transpose_w(const float* __restrict__ Wq,
                                                   const float* __restrict__ Wk,
                                                   const float* __restrict__ Wv,
                                                   const float* __restrict__ Wo,
                                                   u16* __restrict__ wqkvt,
                                                   u16* __restrict__ wot) {
    const int z = blockIdx.z;
    const float* src = (z == 0) ? Wq : (z == 1) ? Wk : (z == 2) ? Wv : Wo;
    u16* dst = (z == 3) ? wot : (wqkvt + (size_t)z * 1024 * 1024);
    __shared__ float tile[32][33];
    const int tx = threadIdx.x, ty = threadIdx.y;  // block (32,8)
    const int nbase = blockIdx.x * 32, kbase = blockIdx.y * 32;
    for (int j = 0; j < 4; ++j)
        tile[ty + j * 8][tx] = src[(size_t)(kbase + ty + j * 8) * 1024 + nbase + tx];
    __syncthreads();
    for (int j = 0; j < 4; ++j)
        dst[(size_t)(nbase + ty + j * 8) * 1024 + kbase + tx] = f2b(tile[tx][ty + j * 8]);
}

__global__ __launch_bounds__(256) void pack_bqkv(const float* __restrict__ bq,
                                                 const float* __restrict__ bk,
                                                 const float* __restrict__ bv,
                                                 float* __restrict__ bqkv) {
    int i = blockIdx.x * 256 + threadIdx.x;  // 3072 total
    bqkv[i] = (i < 1024) ? bq[i] : (i < 2048) ? bk[i - 1024] : bv[i - 2048];
}

// ---------------------------------------------------------------- GEMM (swizzled 128^2)
// C(M,N) = A(M,K) @ Bt(N,K)^T + bias. 128x128 tile, BK=32, 256 thr = 4 waves,
// 3 blocks/CU. Single-barrier DMA ping-pong K-loop.
//
// R16 swizzle: LDS row = 32 u16 = 64B = 4 x 16B chunks; LDS[r][c] holds global
// chunk c ^ ((r>>1)&3) (involution; verified 0-conflict in R3 on this geometry).
//   read side: frag rows r = 16-aligned base + (l&15)  =>  (r>>1)&3 == ((l&15)>>1)&3
//     -> per-lane constant chunk offset g8 = ((l>>4) ^ (((l&15)>>1)&3))*8.
//     bank-group = 16*(r&1) + 4*chunk' : 16 lanes cover all 8 groups twice -> 2-way
//     aliasing only (free, m136).
//   stage side: lane covers slab row srow = l>>2 (slab bases are 16-aligned),
//     LDS chunk l&3 -> global chunk (l&3) ^ ((srow>>1)&3) = (l&3)^((l>>3)&3);
//     each 4-lane row group still reads one contiguous 64B line (coalesced).
// MODE 0: QKV-combined epilogue; MODE 1: fp32 row-major out.
template <int MODE>
__global__ __launch_bounds__(256, 2) void gemm_bt(const u16* __restrict__ A,
                                                  const u16* __restrict__ Bt,
                                                  const float* __restrict__ bias,
                                                  void* __restrict__ Cout,
                                                  void* __restrict__ Cout2,
                                                  int M, int N, int K, int ldc) {
    const int tid = threadIdx.x;
    const int l = tid & 63;
    const int w = tid >> 6;
    const int tileM = blockIdx.x * 128;
    const int tileN = blockIdx.y * 128;

    __shared__ u16 As[2][128 * 32];  // [buf][row][k] stride 32, rows 64B
    __shared__ u16 Bs[2][128 * 32];

    const int srow = l >> 2;
    const int schunk = (l & 3) ^ ((l >> 3) & 3);           // pre-swizzled global chunk
    const int mrow = l & 15;
    const int g8 = ((l >> 4) ^ ((mrow >> 1) & 3)) * 8;     // swizzled read offset
    const int waveM = (w & 1) * 64;
    const int waveN = (w >> 1) * 64;

    const u16* a0 = A + (size_t)(tileM + w * 32 + srow) * K + schunk * 8;
    const u16* a1 = A + (size_t)(tileM + w * 32 + 16 + srow) * K + schunk * 8;
    const u16* b0 = Bt + (size_t)(tileN + w * 32 + srow) * K + schunk * 8;
    const u16* b1 = Bt + (size_t)(tileN + w * 32 + 16 + srow) * K + schunk * 8;

    f32x4 acc[4][4] = {};

    // DMA tile k0=0 into buf 0
    gld16(a0, &As[0][(w * 2) * 512]);
    gld16(a1, &As[0][(w * 2 + 1) * 512]);
    gld16(b0, &Bs[0][(w * 2) * 512]);
    gld16(b1, &Bs[0][(w * 2 + 1) * 512]);
    __syncthreads();

    for (int k0 = 0; k0 < K; k0 += 32) {
        const int cur = (k0 >> 5) & 1;
        if (k0 + 32 < K) {  // DMA next tile into other buf (overlaps compute)
            const int nb = cur ^ 1;
            gld16(a0 + k0 + 32, &As[nb][(w * 2) * 512]);
            gld16(a1 + k0 + 32, &As[nb][(w * 2 + 1) * 512]);
            gld16(b0 + k0 + 32, &Bs[nb][(w * 2) * 512]);
            gld16(b1 + k0 + 32, &Bs[nb][(w * 2 + 1) * 512]);
        }

        bf16x8 af[4], bf[4];
        for (int im = 0; im < 4; ++im)
            af[im] = *(const bf16x8*)&As[cur][(waveM + im * 16 + mrow) * 32 + g8];
        for (int in = 0; in < 4; ++in)
            bf[in] = *(const bf16x8*)&Bs[cur][(waveN + in * 16 + mrow) * 32 + g8];
        for (int im = 0; im < 4; ++im)
            for (int in = 0; in < 4; ++in)
                acc[im][in] = mfma16(af[im], bf[in], acc[im][in]);
        __syncthreads();  // one barrier/iter: drains DMA (vmcnt) + LDS reads (lgkm)
    }

    // epilogue. C/D layout: row=(l>>4)*4+r, col=l&15  [m89/m91]
    const int rbase = (l >> 4) * 4;
    for (int im = 0; im < 4; ++im) {
        for (int in = 0; in < 4; ++in) {
            const int gm0 = tileM + waveM + im * 16 + rbase;
            const int gn = tileN + waveN + in * 16 + (l & 15);
            const float bv_ = bias[gn];
            if (MODE == 1) {
                float* out = (float*)Cout;
                for (int r = 0; r < 4; ++r)
                    out[(size_t)(gm0 + r) * ldc + gn] = acc[im][in][r] + bv_;
            } else if (tileN < 2048) {
                // fold softmax scale * log2e into Q
                const float qs = (tileN < 1024) ? 0.125f * 1.4426950408889634f : 1.0f;
                u16* out = (u16*)Cout;  // qk, row-major (token, 2048)
                for (int r = 0; r < 4; ++r)
                    out[(size_t)(gm0 + r) * 2048 + gn] = f2b((acc[im][in][r] + bv_) * qs);
            } else {
                u16* out = (u16*)Cout2;  // V^T scatter (B,H,Dh,S)
                const int b = gm0 >> 11, s0 = gm0 & 2047;
                const int gn2 = gn - 2048;
                const int h = gn2 >> 6, dh = gn2 & 63;
                ushort4 u;
                u.x = f2b(acc[im][in][0] + bv_);
                u.y = f2b(acc[im][in][1] + bv_);
                u.z = f2b(acc[im][in][2] + bv_);
                u.w = f2b(acc[im][in][3] + bv_);
                *(ushort4*)&out[((size_t)((b * 16 + h) * 64 + dh)) * 2048 + s0] = u;
            }
        }
    }
}

// ---------------------------------------------------------------- flash attention
// R11 winner, unchanged: 256 thr = 4 waves, 128 queries/block, ONE barrier/round,
// K/V staged by global_load_lds DMA into double-buffered XOR-swizzled LDS tiles,
// max-free softmax with epilogue-only denominator reduction.
__global__ __launch_bounds__(256, 2) void attn_kernel(const u16* __restrict__ qk,
                                                      const u16* __restrict__ vt,
                                                      u16* __restrict__ attn) {
    const int bh = blockIdx.x;
    const int qt = 15 - (int)blockIdx.y;  // big q-tiles launch first
    const int b = bh >> 4, h = bh & 15;
    const int q0 = qt * 128;
    const int tid = threadIdx.x, l = tid & 63, w = tid >> 6;
    const int q = l & 15;   // query column within group
    const int g = l >> 4;   // k-group
    const int g8 = g * 8;

    __shared__ u16 Ks[2][64 * 64];  // [buf][key][dh]   XOR-swizzled chunks
    __shared__ u16 Vs[2][64 * 64];  // [buf][dh][key]   XOR-swizzled chunks
    __shared__ u16 Ps[128 * 72];    // Q staging, then per-wave P slabs [query][key]

    const int sr8 = l >> 3;
    const int gc = (l & 7) ^ sr8;
    const u16* kgl = qk + (size_t)(b * 2048 + w * 16 + sr8) * 2048 + 1024 + h * 64 + gc * 8;
    const u16* vgl = vt + (size_t)(bh * 64 + w * 16 + sr8) * 2048 + gc * 8;

    for (int i = 0; i < 4; ++i) {
        const int idx = i * 256 + tid;
        const int row = idx >> 3, ch = idx & 7;
        *(uint4*)&Ps[row * 72 + ch * 8] =
            *(const uint4*)&qk[(size_t)(b * 2048 + q0 + row) * 2048 + h * 64 + ch * 8];
    }
    for (int j = 0; j < 2; ++j) {
        gld16(kgl + (size_t)(j * 8) * 2048, &Ks[0][(w * 16 + j * 8) * 64]);
        gld16(vgl + (size_t)(j * 8) * 2048, &Vs[0][(w * 16 + j * 8) * 64]);
    }
    __syncthreads();

    bf16x8 qb[2][2];
    for (int c = 0; c < 2; ++c) {
        qb[c][0] = *(const bf16x8*)&Ps[(w * 32 + c * 16 + q) * 72 + g8];
        qb[c][1] = *(const bf16x8*)&Ps[(w * 32 + c * 16 + q) * 72 + 32 + g8];
    }

    const int cl0 = ((g) ^ (q & 7)) * 8;
    const int cl1 = ((4 + g) ^ (q & 7)) * 8;

    float li[2] = {0.f, 0.f};
    f32x4 o[2][4] = {};
    const int tmax = 2 * qt + 1;
    const int tdiag = (q0 + w * 32 + 31) >> 6;

    for (int t = 0; t <= tmax; ++t) {
        const int tp = (t < tmax) ? t + 1 : tmax;
        const int nb = (t + 1) & 1;
        for (int j = 0; j < 2; ++j) {
            gld16(kgl + (size_t)(tp * 64 + j * 8) * 2048, &Ks[nb][(w * 16 + j * 8) * 64]);
            gld16(vgl + (size_t)(j * 8) * 2048 + tp * 64, &Vs[nb][(w * 16 + j * 8) * 64]);
        }

        if (t <= tdiag) {
            const int cb0 = t & 1;
            const int kv0 = t * 64;
            const u16* ks = &Ks[cb0][0];
            const u16* vs = &Vs[cb0][0];

            f32x4 st[2][4] = {};
            for (int cb = 0; cb < 4; ++cb) {
                bf16x8 ka0 = *(const bf16x8*)&ks[(cb * 16 + q) * 64 + cl0];
                bf16x8 ka1 = *(const bf16x8*)&ks[(cb * 16 + q) * 64 + cl1];
                st[0][cb] = mfma16(ka0, qb[0][0], st[0][cb]);
                st[1][cb] = mfma16(ka0, qb[1][0], st[1][cb]);
                st[0][cb] = mfma16(ka1, qb[0][1], st[0][cb]);
                st[1][cb] = mfma16(ka1, qb[1][1], st[1][cb]);
            }
            for (int c = 0; c < 2; ++c) {
                if (t == tdiag) {
                    const int qg = q0 + w * 32 + c * 16 + q;
                    for (int cb = 0; cb < 4; ++cb)
                        for (int r = 0; r < 4; ++r) {
                            const int key = kv0 + cb * 16 + g * 4 + r;
                            if (key > qg) st[c][cb][r] = -1e30f;
                        }
                }
                float ps = 0.f;
                for (int cb = 0; cb < 4; ++cb)
                    for (int r = 0; r < 4; ++r) {
                        const float p = __builtin_amdgcn_exp2f(st[c][cb][r]);
                        st[c][cb][r] = p;
                        ps += p;
                    }
                li[c] += ps;
                for (int cb = 0; cb < 4; ++cb) {
                    ushort4 u;
                    u.x = f2b(st[c][cb][0]); u.y = f2b(st[c][cb][1]);
                    u.z = f2b(st[c][cb][2]); u.w = f2b(st[c][cb][3]);
                    *(ushort4*)&Ps[(w * 32 + c * 16 + q) * 72 + cb * 16 + g * 4] = u;
                }
            }
            __builtin_amdgcn_s_waitcnt(0xC07F);  // lgkmcnt(0); DS in-order per wave
            for (int cb = 0; cb < 4; ++cb) {
                bf16x8 va0 = *(const bf16x8*)&vs[(cb * 16 + q) * 64 + cl0];
                bf16x8 va1 = *(const bf16x8*)&vs[(cb * 16 + q) * 64 + cl1];
                bf16x8 pb00 = *(const bf16x8*)&Ps[(w * 32 + q) * 72 + g8];
                bf16x8 pb01 = *(const bf16x8*)&Ps[(w * 32 + q) * 72 + 32 + g8];
                bf16x8 pb10 = *(const bf16x8*)&Ps[(w * 32 + 16 + q) * 72 + g8];
                bf16x8 pb11 = *(const bf16x8*)&Ps[(w * 32 + 16 + q) * 72 + 32 + g8];
                o[0][cb] = mfma16(va0, pb00, o[0][cb]);
                o[1][cb] = mfma16(va0, pb10, o[1][cb]);
                o[0][cb] = mfma16(va1, pb01, o[0][cb]);
                o[1][cb] = mfma16(va1, pb11, o[1][cb]);
            }
        }
        __syncthreads();
    }

    for (int c = 0; c < 2; ++c) {
        float ps = li[c];
        ps += __shfl_xor(ps, 16);
        ps += __shfl_xor(ps, 32);
        const float inv = 1.0f / ps;
        const size_t tok = (size_t)(b * 2048 + q0 + w * 32 + c * 16 + q);
        for (int cb = 0; cb < 4; ++cb) {
            ushort4 u;
            u.x = f2b(o[c][cb][0] * inv); u.y = f2b(o[c][cb][1] * inv);
            u.z = f2b(o[c][cb][2] * inv); u.w = f2b(o[c][cb][3] * inv);
            *(ushort4*)&attn[tok * 1024 + h * 64 + cb * 16 + g * 4] = u;
        }
    }
}

// ---------------------------------------------------------------- launch
extern "C" void kernel_launch(void* const* d_in, const int* in_sizes, int n_in,
                              void* d_out, int out_size, void* d_ws, size_t ws_size,
                              hipStream_t stream) {
    const float* x  = (const float*)d_in[0];
    const float* Wq = (const float*)d_in[1];
    const float* bq = (const float*)d_in[2];
    const float* Wk = (const float*)d_in[3];
    const float* bk = (const float*)d_in[4];
    const float* Wv = (const float*)d_in[5];
    const float* bv = (const float*)d_in[6];
    const float* Wo = (const float*)d_in[7];
    const float* bo = (const float*)d_in[8];
    float* out = (float*)d_out;

    char* ws = (char*)d_ws;
    size_t off = 0;
    auto alloc = [&](size_t bytes) -> void* {
        void* p = ws + off;
        off += (bytes + 255) & ~(size_t)255;
        return p;
    };
    u16*   xb    = (u16*)alloc(8192ull * 1024 * 2);   // x bf16
    u16*   wqkvt = (u16*)alloc(3072ull * 1024 * 2);   // [Wq|Wk|Wv]^T (N,K)
    u16*   wot   = (u16*)alloc(1024ull * 1024 * 2);   // Wo^T
    float* bqkv  = (float*)alloc(3072ull * 4);
    u16*   qk    = (u16*)alloc(8192ull * 2048 * 2);   // [q|k] (token, 2048)
    u16*   vt    = (u16*)alloc(8192ull * 1024 * 2);   // V^T (B,H,Dh,S)
    u16*   attn  = (u16*)alloc(8192ull * 1024 * 2);   // attention out (token, D)

    convert_x<<<8192, 256, 0, stream>>>(x, xb, 8192 * 1024 / 4);
    transpose_w<<<dim3(32, 32, 4), dim3(32, 8), 0, stream>>>(Wq, Wk, Wv, Wo, wqkvt, wot);
    pack_bqkv<<<12, 256, 0, stream>>>(bq, bk, bv, bqkv);
    gemm_bt<0><<<dim3(64, 24), 256, 0, stream>>>(xb, wqkvt, bqkv, qk, vt, 8192, 3072, 1024, 0);
    attn_kernel<<<dim3(64, 16), 256, 0, stream>>>(qk, vt, attn);
    gemm_bt<1><<<dim3(64, 8), 256, 0, stream>>>(attn, wot, bo, out, nullptr, 8192, 1024, 1024, 1024);
}